// Round 17
// baseline (90.656 us; speedup 1.0000x reference)
//
#include <hip/hip_runtime.h>
#include <hip/hip_bf16.h>

// Sparse bottleneck block, B=32, Cin=Cout=256, width=64, H=W=56. f32 in/out.
// Round 17: R16 with the compile fix — nontemporal store uses ext-vector
// f32x4 (clang vector type) instead of HIP_vector_type float4.
// (a) nontemporal out-stores in k3 (out never re-read; stop evicting x from
// L3), (b) T1 XCD swizzle on k1. Pipeline: kw | k1 | k2 | k3.

#define BATCH 32
#define CIN   256
#define WIDTH 64
#define COUT  256
#define HH    56
#define WW    56
#define HW    3136
#define EPS   1e-5f
#define XSTR  40       // k1 xs row stride in u16 (4-way store banks)
#define H1ROW 7424     // bytes per padded row: 58 px * 128 B

typedef __attribute__((ext_vector_type(8))) short bf16x8;
typedef __attribute__((ext_vector_type(4))) float f32x4;

static __device__ __forceinline__ unsigned short f2bf(float f) {
    __hip_bfloat16 h = __float2bfloat16(f);
    return *reinterpret_cast<unsigned short*>(&h);
}

// ---------------------------------------------------------------------------
// kw: pack w1/w2 A-frags, w3 B-frags (w3q); block 272 computes bn tables.
// ---------------------------------------------------------------------------
__global__ __launch_bounds__(256) void kw_pack(
    const float* __restrict__ w1, const float* __restrict__ w2,
    const float* __restrict__ w3, __hip_bfloat16* __restrict__ w1p,
    __hip_bfloat16* __restrict__ w2p, __hip_bfloat16* __restrict__ w3q,
    const float* __restrict__ g1, const float* __restrict__ b1,
    const float* __restrict__ m1, const float* __restrict__ v1,
    const float* __restrict__ g2, const float* __restrict__ b2,
    const float* __restrict__ m2, const float* __restrict__ v2,
    const float* __restrict__ g3, const float* __restrict__ b3,
    const float* __restrict__ m3, const float* __restrict__ v3,
    float* __restrict__ tabs)
{
    if (blockIdx.x == 272) {
        for (int t = threadIdx.x; t < 384; t += 256) {
            if (t < 64) {
                float sc = g1[t] * rsqrtf(v1[t] + EPS);
                tabs[t] = sc; tabs[64 + t] = b1[t] - m1[t] * sc;
            } else if (t < 128) {
                int o = t - 64;
                float sc = g2[o] * rsqrtf(v2[o] + EPS);
                tabs[128 + o] = sc; tabs[192 + o] = b2[o] - m2[o] * sc;
            } else {
                int o = t - 128;
                float sc = g3[o] * rsqrtf(v3[o] + EPS);
                tabs[256 + o] = sc; tabs[512 + o] = b3[o] - m3[o] * sc;
            }
        }
        return;
    }
    int idx = blockIdx.x * 256 + threadIdx.x;
    if (idx < 16384) {                       // w1p: kt 0..7, mt 0..3
        int j = idx & 7, l = (idx >> 3) & 63;
        int mt = (idx >> 9) & 3, kt = idx >> 11;
        int o = mt * 16 + (l & 15);
        int c = kt * 32 + (l >> 4) * 8 + j;
        *reinterpret_cast<unsigned short*>(w1p + idx) = f2bf(w1[o * CIN + c]);
    } else if (idx < 16384 + 36864) {        // w2p: tap 0..8, kt 0..1, mt 0..3
        int i2 = idx - 16384;
        int j = i2 & 7, l = (i2 >> 3) & 63;
        int mt = (i2 >> 9) & 3, kt = (i2 >> 11) & 1, tap = i2 >> 12;
        int o = mt * 16 + (l & 15);
        int c = kt * 32 + (l >> 4) * 8 + j;
        *reinterpret_cast<unsigned short*>(w2p + i2) =
            f2bf(w2[(o * WIDTH + c) * 9 + tap]);
    } else if (idx < 16384 + 36864 + 16384) { // w3q: kt 0..1, ot 0..15
        int i3 = idx - 16384 - 36864;
        int j = i3 & 7, l = (i3 >> 3) & 63;
        int ot = (i3 >> 9) & 15, kt = i3 >> 13;
        int oc = ot * 16 + (l & 15);
        int c = kt * 32 + (l >> 4) * 8 + j;
        *reinterpret_cast<unsigned short*>(w3q + i3) = f2bf(w3[oc * WIDTH + c]);
    }
}

// ---------------------------------------------------------------------------
// k1: h1g = relu(bn1(conv1(x))) bf16 chan-last padded [58][58][64]; f32 mask.
// h1g px-rows stored pre-swizzled (u16 off ^= (pxp&7)<<3).
// T1 XCD swizzle: 1568 = 8*196 blocks; each XCD owns 4 whole images.
// ---------------------------------------------------------------------------
__global__ __launch_bounds__(256) void k1_mfma(
    const float* __restrict__ x, const __hip_bfloat16* __restrict__ w1p,
    const float* __restrict__ sc1, const float* __restrict__ sh1,
    const float* __restrict__ mw, const float* __restrict__ mb,
    __hip_bfloat16* __restrict__ h1g, float* __restrict__ mask)
{
    __shared__ __align__(16) unsigned short xs[2][64 * XSTR];
    __shared__ __align__(16) float mtab[16][68];

    const int tid = threadIdx.x;
    const int l = tid & 63, w = tid >> 6;
    const int ln = l & 15, lg = l >> 4;

    // T1 bijective XCD swizzle: grid (49, 32) -> n consecutive per XCD
    const int flat = blockIdx.x + 49 * blockIdx.y;
    const int n = (flat & 7) * 196 + (flat >> 3);      // 1568/8 = 196
    const int px0 = (n % 49) * 64;
    const int b = n / 49;

    const float* __restrict__ xb = x + (size_t)b * CIN * HW;
    const bf16x8* __restrict__ w1v = reinterpret_cast<const bf16x8*>(w1p);

    const int chA = tid >> 4;          // 0..15
    const int pxs = (tid & 15) * 4;    // 0..60
    float msum[4] = {0.f, 0.f, 0.f, 0.f};

    auto STAGE = [&](int kt, int bufi) {
        const float* xp = xb + (size_t)(kt * 32 + chA) * HW + px0 + pxs;
        float4 va = *reinterpret_cast<const float4*>(xp);
        float4 vb = *reinterpret_cast<const float4*>(xp + (size_t)16 * HW);
        float mwa = mw[kt * 32 + chA], mwb = mw[kt * 32 + 16 + chA];
        msum[0] += va.x * mwa + vb.x * mwb;
        msum[1] += va.y * mwa + vb.y * mwb;
        msum[2] += va.z * mwa + vb.z * mwb;
        msum[3] += va.w * mwa + vb.w * mwb;
        unsigned base = (unsigned)pxs * XSTR + chA;
        xs[bufi][base + 0 * XSTR] = f2bf(va.x);
        xs[bufi][base + 1 * XSTR] = f2bf(va.y);
        xs[bufi][base + 2 * XSTR] = f2bf(va.z);
        xs[bufi][base + 3 * XSTR] = f2bf(va.w);
        xs[bufi][base + 16 + 0 * XSTR] = f2bf(vb.x);
        xs[bufi][base + 16 + 1 * XSTR] = f2bf(vb.y);
        xs[bufi][base + 16 + 2 * XSTR] = f2bf(vb.z);
        xs[bufi][base + 16 + 3 * XSTR] = f2bf(vb.w);
    };

    f32x4 acc[4];
    #pragma unroll
    for (int m = 0; m < 4; ++m) acc[m] = f32x4{0.f, 0.f, 0.f, 0.f};

    STAGE(0, 0);
    __syncthreads();

    const unsigned fidx = (unsigned)(w * 16 + ln) * XSTR + lg * 8;
    #pragma unroll
    for (int kt = 0; kt < 8; ++kt) {
        const int cur = kt & 1;
        if (kt < 7) STAGE(kt + 1, cur ^ 1);
        bf16x8 bfr = *reinterpret_cast<const bf16x8*>(&xs[cur][fidx]);
        #pragma unroll
        for (int mt = 0; mt < 4; ++mt) {
            bf16x8 a = w1v[(kt * 4 + mt) * 64 + l];
            acc[mt] = __builtin_amdgcn_mfma_f32_16x16x32_bf16(a, bfr, acc[mt], 0, 0, 0);
        }
        __syncthreads();
    }

    *reinterpret_cast<float4*>(&mtab[chA][pxs]) =
        make_float4(msum[0], msum[1], msum[2], msum[3]);
    __syncthreads();
    if (tid < 64) {
        float s = 0.f;
        #pragma unroll
        for (int g = 0; g < 16; ++g) s += mtab[g][tid];
        mask[b * HW + px0 + tid] = (s + mb[0] >= 0.f) ? 1.f : 0.f;
    }

    const int p = px0 + w * 16 + ln;
    const int y = p / 56, xcn = p - y * 56;
    const int pxp = xcn + 1;                       // padded col
    const unsigned key = (unsigned)(pxp & 7) << 3; // u16-unit XOR key
    const size_t rowbase = (((size_t)b * 58 + y + 1) * 58 + pxp) * 64;
    #pragma unroll
    for (int mt = 0; mt < 4; ++mt) {
        int ob = mt * 16 + lg * 4;
        ushort4 u;
        u.x = f2bf(fmaxf(acc[mt][0] * sc1[ob + 0] + sh1[ob + 0], 0.f));
        u.y = f2bf(fmaxf(acc[mt][1] * sc1[ob + 1] + sh1[ob + 1], 0.f));
        u.z = f2bf(fmaxf(acc[mt][2] * sc1[ob + 2] + sh1[ob + 2], 0.f));
        u.w = f2bf(fmaxf(acc[mt][3] * sc1[ob + 3] + sh1[ob + 3], 0.f));
        *reinterpret_cast<ushort4*>(h1g + rowbase + (ob ^ key)) = u;
    }
}

// ---------------------------------------------------------------------------
// k2: h2 = relu(bn2(conv2(h1 * dilate(mask)))) * mask -> bf16 chan-last.
// XCD swizzle (R15). Unchanged.
// ---------------------------------------------------------------------------
__global__ __launch_bounds__(256) void k2_mfma(
    const __hip_bfloat16* __restrict__ h1g,
    const __hip_bfloat16* __restrict__ w2p,
    const float* __restrict__ sc2, const float* __restrict__ sh2,
    const float* __restrict__ mask, __hip_bfloat16* __restrict__ h2)
{
    __shared__ __align__(16) char smem[30720];   // 4 rows * 7424

    const int tid = threadIdx.x;
    const int l = tid & 63, w = tid >> 6;

    const int flat = blockIdx.x + 28 * blockIdx.y;
    const int n = (flat & 7) * 112 + (flat >> 3);      // 896/8 = 112
    const int yr0 = (n % 28) * 2;
    const int b = n / 28;

    const int yrow = yr0 + (w & 1);              // output row
    const int mh = w >> 1;                       // oc half
    const int ln = l & 15, lg = l >> 4;

    {
        const char* src = (const char*)h1g + ((size_t)b * 58 + yr0) * H1ROW;
        #pragma unroll
        for (int t = 0; t < 8; ++t) {
            int c = t * 4 + w;                   // wave-uniform chunk id
            if (c < 29) {
                __builtin_amdgcn_global_load_lds(
                    (const __attribute__((address_space(1))) void*)(src + c * 1024 + l * 16),
                    (__attribute__((address_space(3))) void*)(smem + c * 1024),
                    16, 0, 0);
            }
        }
    }

    const bf16x8* __restrict__ w2v = reinterpret_cast<const bf16x8*>(w2p);

    f32x4 acc[2][4];
    #pragma unroll
    for (int i = 0; i < 2; ++i)
        #pragma unroll
        for (int j = 0; j < 4; ++j) acc[i][j] = f32x4{0.f, 0.f, 0.f, 0.f};

    __syncthreads();   // drains global_load_lds + sync

    // dilate-zero pass: 232 px = 4 rows x 58 cols
    if (tid < 232) {
        const int pr = tid / 58;
        const int pc = tid - pr * 58;
        const int gr = yr0 + pr;
        bool zero;
        if (gr == 0 || gr == 57 || pc == 0 || pc == 57) {
            zero = true;
        } else {
            const int y = gr - 1, xc = pc - 1;
            float mx = 0.f;
            #pragma unroll
            for (int dy = -1; dy <= 1; ++dy)
                #pragma unroll
                for (int dx = -1; dx <= 1; ++dx) {
                    int yy = y + dy, xx = xc + dx;
                    if (yy >= 0 && yy < HH && xx >= 0 && xx < WW)
                        mx = fmaxf(mx, mask[b * HW + yy * WW + xx]);
                }
            zero = (mx < 0.5f);
        }
        if (zero) {
            uint4* q = reinterpret_cast<uint4*>(smem + pr * H1ROW + pc * 128);
            uint4 zz = make_uint4(0u, 0u, 0u, 0u);
            #pragma unroll
            for (int k = 0; k < 8; ++k) q[k] = zz;
        }
    }
    __syncthreads();

    #pragma unroll
    for (int dy = 0; dy < 3; ++dy) {
        const int lr = (w & 1) + dy;
        #pragma unroll
        for (int dx = 0; dx < 3; ++dx) {
            const int tap = dy * 3 + dx;
            #pragma unroll
            for (int kt = 0; kt < 2; ++kt) {
                bf16x8 a0 = w2v[((tap * 2 + kt) * 4 + mh * 2 + 0) * 64 + l];
                bf16x8 a1 = w2v[((tap * 2 + kt) * 4 + mh * 2 + 1) * 64 + l];
                bf16x8 bf[4];
                #pragma unroll
                for (int nt = 0; nt < 4; ++nt) {
                    int colp = nt * 16 + ln + dx;
                    unsigned off = (unsigned)lr * H1ROW + (unsigned)colp * 128
                                 + (((unsigned)(kt * 64 + lg * 16))
                                    ^ (((unsigned)colp & 7u) << 4));
                    bf[nt] = *reinterpret_cast<const bf16x8*>(smem + off);
                }
                #pragma unroll
                for (int nt = 0; nt < 4; ++nt) {
                    acc[0][nt] = __builtin_amdgcn_mfma_f32_16x16x32_bf16(
                        a0, bf[nt], acc[0][nt], 0, 0, 0);
                    acc[1][nt] = __builtin_amdgcn_mfma_f32_16x16x32_bf16(
                        a1, bf[nt], acc[1][nt], 0, 0, 0);
                }
            }
        }
    }

    #pragma unroll
    for (int nt = 0; nt < 4; ++nt) {
        int xc = nt * 16 + ln;
        if (xc < WW) {
            int p = yrow * WW + xc;
            float mkv = mask[b * HW + p];
            #pragma unroll
            for (int mi = 0; mi < 2; ++mi) {
                int ob = (mh * 2 + mi) * 16 + lg * 4;
                ushort4 u;
                u.x = f2bf(fmaxf(acc[mi][nt][0] * sc2[ob + 0] + sh2[ob + 0], 0.f) * mkv);
                u.y = f2bf(fmaxf(acc[mi][nt][1] * sc2[ob + 1] + sh2[ob + 1], 0.f) * mkv);
                u.z = f2bf(fmaxf(acc[mi][nt][2] * sc2[ob + 2] + sh2[ob + 2], 0.f) * mkv);
                u.w = f2bf(fmaxf(acc[mi][nt][3] * sc2[ob + 3] + sh2[ob + 3], 0.f) * mkv);
                *reinterpret_cast<ushort4*>(h2 + ((size_t)b * HW + p) * 64 + ob) = u;
            }
        }
    }
}

// ---------------------------------------------------------------------------
// k3: out = relu(x + bn3(conv3(h2)) * mask). R15 structure + XCD swizzle;
// out stored NONTEMPORAL via ext-vector f32x4 (valid builtin operand).
// ---------------------------------------------------------------------------
__global__ __launch_bounds__(256) void k3_mfma(
    const __hip_bfloat16* __restrict__ h2, const __hip_bfloat16* __restrict__ w3q,
    const float* __restrict__ sc3, const float* __restrict__ sh3,
    const float* __restrict__ x, const float* __restrict__ mask,
    float* __restrict__ out)
{
    __shared__ __align__(16) float h3s[128][68];   // 34816 B

    const int tid = threadIdx.x;
    const int l = tid & 63, w = tid >> 6;
    const int ln = l & 15, lg = l >> 4;

    // T1 bijective XCD swizzle: grid (56, 32, 2) -> n consecutive per XCD
    const int flat = blockIdx.x + 56 * (blockIdx.y + 32 * blockIdx.z);
    const int n = (flat & 7) * 448 + (flat >> 3);      // 3584/8 = 448
    const int yr = n % 56;
    const int b = (n / 56) & 31;
    const int z = n / (56 * 32);

    const bf16x8* __restrict__ h2v = reinterpret_cast<const bf16x8*>(h2)
                                   + ((size_t)b * HW + yr * WW) * 8;
    const bf16x8* __restrict__ w3v = reinterpret_cast<const bf16x8*>(w3q);

    // ---- phase 1: MFMA ----
    bf16x8 af[2][4];   // [kt][pt]
    #pragma unroll
    for (int kt = 0; kt < 2; ++kt)
        #pragma unroll
        for (int pt = 0; pt < 4; ++pt)
            af[kt][pt] = h2v[(pt * 16 + ln) * 8 + kt * 4 + lg];  // px>=56 overread OK
    bf16x8 bw[2][2];   // [kt][ot]
    #pragma unroll
    for (int kt = 0; kt < 2; ++kt)
        #pragma unroll
        for (int ot = 0; ot < 2; ++ot)
            bw[kt][ot] = w3v[(kt * 16 + w * 4 + z * 2 + ot) * 64 + l];

    f32x4 acc[4][2];   // [pt][ot]
    #pragma unroll
    for (int p = 0; p < 4; ++p)
        #pragma unroll
        for (int o = 0; o < 2; ++o) acc[p][o] = f32x4{0.f, 0.f, 0.f, 0.f};

    #pragma unroll
    for (int kt = 0; kt < 2; ++kt)
        #pragma unroll
        for (int ot = 0; ot < 2; ++ot)
            #pragma unroll
            for (int pt = 0; pt < 4; ++pt)
                acc[pt][ot] = __builtin_amdgcn_mfma_f32_16x16x32_bf16(
                    af[kt][pt], bw[kt][ot], acc[pt][ot], 0, 0, 0);

    // ---- dump raw acc to LDS (px 56..63 garbage, never read) ----
    #pragma unroll
    for (int ot = 0; ot < 2; ++ot) {
        const int r = w * 32 + ot * 16 + ln;
        #pragma unroll
        for (int pt = 0; pt < 4; ++pt)
            *reinterpret_cast<f32x4*>(&h3s[r][pt * 16 + lg * 4]) = acc[pt][ot];
    }
    __syncthreads();

    // ---- phase 2: row-contiguous residual + nontemporal store ----
    const int tc = tid & 15, tr0 = tid >> 4;
    if (tc < 14) {
        const int px4 = tc * 4;
        const float4 mk = *reinterpret_cast<const float4*>(
            &mask[(size_t)b * HW + yr * WW + px4]);
        #pragma unroll
        for (int pass = 0; pass < 8; ++pass) {
            const int r = pass * 16 + tr0;
            const int oc = ((r >> 5) << 6) + z * 32 + (r & 31);
            const float4 v = *reinterpret_cast<const float4*>(&h3s[r][px4]);
            const float sc = sc3[oc], sh = sh3[oc];
            const size_t idx = ((size_t)b * COUT + oc) * HW + yr * WW + px4;
            const float4 xv = *reinterpret_cast<const float4*>(&x[idx]);
            f32x4 o4;
            o4[0] = fmaxf(xv.x + (v.x * sc + sh) * mk.x, 0.f);
            o4[1] = fmaxf(xv.y + (v.y * sc + sh) * mk.y, 0.f);
            o4[2] = fmaxf(xv.z + (v.z * sc + sh) * mk.z, 0.f);
            o4[3] = fmaxf(xv.w + (v.w * sc + sh) * mk.w, 0.f);
            __builtin_nontemporal_store(o4, reinterpret_cast<f32x4*>(&out[idx]));
        }
    }
}

// ---------------------------------------------------------------------------
extern "C" void kernel_launch(void* const* d_in, const int* in_sizes, int n_in,
                              void* d_out, int out_size, void* d_ws, size_t ws_size,
                              hipStream_t stream)
{
    const float* x  = (const float*)d_in[0];
    const float* w1 = (const float*)d_in[1];
    const float* w2 = (const float*)d_in[2];
    const float* w3 = (const float*)d_in[3];
    const float* g1 = (const float*)d_in[4];
    const float* b1 = (const float*)d_in[5];
    const float* m1 = (const float*)d_in[6];
    const float* v1 = (const float*)d_in[7];
    const float* g2 = (const float*)d_in[8];
    const float* b2 = (const float*)d_in[9];
    const float* m2 = (const float*)d_in[10];
    const float* v2 = (const float*)d_in[11];
    const float* g3 = (const float*)d_in[12];
    const float* b3 = (const float*)d_in[13];
    const float* m3 = (const float*)d_in[14];
    const float* v3 = (const float*)d_in[15];
    const float* mw = (const float*)d_in[16];
    const float* mb = (const float*)d_in[17];
    float* outp = (float*)d_out;

    // ws layout
    char* p = (char*)d_ws;
    __hip_bfloat16* h1g = (__hip_bfloat16*)p;  p += (size_t)BATCH * 3364 * 64 * 2; // 13.8 MB
    __hip_bfloat16* h2  = (__hip_bfloat16*)p;  p += (size_t)BATCH * HW * 64 * 2;   // 12.8 MB
    float* mask = (float*)p;                   p += (size_t)BATCH * HW * 4;        // 0.4 MB
    __hip_bfloat16* w1p = (__hip_bfloat16*)p;  p += 16384 * 2;
    __hip_bfloat16* w2p = (__hip_bfloat16*)p;  p += 36864 * 2;
    __hip_bfloat16* w3q = (__hip_bfloat16*)p;  p += 16384 * 2;
    float* tabs = (float*)p;
    float* sc1 = tabs;       float* sh1 = tabs + 64;
    float* sc2 = tabs + 128; float* sh2 = tabs + 192;
    float* sc3 = tabs + 256; float* sh3 = tabs + 512;

    kw_pack<<<dim3(273), dim3(256), 0, stream>>>(w1, w2, w3, w1p, w2p, w3q,
                                                 g1, b1, m1, v1, g2, b2, m2, v2,
                                                 g3, b3, m3, v3, tabs);

    k1_mfma<<<dim3(49, BATCH), dim3(256), 0, stream>>>(x, w1p, sc1, sh1, mw, mb,
                                                       h1g, mask);

    k2_mfma<<<dim3(28, BATCH), dim3(256), 0, stream>>>(h1g, w2p, sc2, sh2,
                                                       mask, h2);

    k3_mfma<<<dim3(HH, BATCH, 2), dim3(256), 0, stream>>>(h2, w3q, sc3, sh3,
                                                          x, mask, outp);
}

// Round 18
// 88.455 us; speedup vs baseline: 1.0249x; 1.0249x over previous
//
#include <hip/hip_runtime.h>
#include <hip/hip_bf16.h>

// Sparse bottleneck block, B=32, Cin=Cout=256, width=64, H=W=56. f32 in/out.
// Round 18: exact revert to R15 (best, 88.5us). R16/17's nontemporal store +
// k1 swizzle regressed (90.7) and are dropped. k2/k3 keep the T1 bijective
// XCD swizzle (the proven +8us lever). Pipeline: kw | k1 | k2 | k3.

#define BATCH 32
#define CIN   256
#define WIDTH 64
#define COUT  256
#define HH    56
#define WW    56
#define HW    3136
#define EPS   1e-5f
#define XSTR  40       // k1 xs row stride in u16 (4-way store banks)
#define H1ROW 7424     // bytes per padded row: 58 px * 128 B

typedef __attribute__((ext_vector_type(8))) short bf16x8;
typedef __attribute__((ext_vector_type(4))) float f32x4;

static __device__ __forceinline__ unsigned short f2bf(float f) {
    __hip_bfloat16 h = __float2bfloat16(f);
    return *reinterpret_cast<unsigned short*>(&h);
}

// ---------------------------------------------------------------------------
// kw: pack w1/w2 A-frags, w3 B-frags (w3q); block 272 computes bn tables.
// ---------------------------------------------------------------------------
__global__ __launch_bounds__(256) void kw_pack(
    const float* __restrict__ w1, const float* __restrict__ w2,
    const float* __restrict__ w3, __hip_bfloat16* __restrict__ w1p,
    __hip_bfloat16* __restrict__ w2p, __hip_bfloat16* __restrict__ w3q,
    const float* __restrict__ g1, const float* __restrict__ b1,
    const float* __restrict__ m1, const float* __restrict__ v1,
    const float* __restrict__ g2, const float* __restrict__ b2,
    const float* __restrict__ m2, const float* __restrict__ v2,
    const float* __restrict__ g3, const float* __restrict__ b3,
    const float* __restrict__ m3, const float* __restrict__ v3,
    float* __restrict__ tabs)
{
    if (blockIdx.x == 272) {
        for (int t = threadIdx.x; t < 384; t += 256) {
            if (t < 64) {
                float sc = g1[t] * rsqrtf(v1[t] + EPS);
                tabs[t] = sc; tabs[64 + t] = b1[t] - m1[t] * sc;
            } else if (t < 128) {
                int o = t - 64;
                float sc = g2[o] * rsqrtf(v2[o] + EPS);
                tabs[128 + o] = sc; tabs[192 + o] = b2[o] - m2[o] * sc;
            } else {
                int o = t - 128;
                float sc = g3[o] * rsqrtf(v3[o] + EPS);
                tabs[256 + o] = sc; tabs[512 + o] = b3[o] - m3[o] * sc;
            }
        }
        return;
    }
    int idx = blockIdx.x * 256 + threadIdx.x;
    if (idx < 16384) {                       // w1p: kt 0..7, mt 0..3
        int j = idx & 7, l = (idx >> 3) & 63;
        int mt = (idx >> 9) & 3, kt = idx >> 11;
        int o = mt * 16 + (l & 15);
        int c = kt * 32 + (l >> 4) * 8 + j;
        *reinterpret_cast<unsigned short*>(w1p + idx) = f2bf(w1[o * CIN + c]);
    } else if (idx < 16384 + 36864) {        // w2p: tap 0..8, kt 0..1, mt 0..3
        int i2 = idx - 16384;
        int j = i2 & 7, l = (i2 >> 3) & 63;
        int mt = (i2 >> 9) & 3, kt = (i2 >> 11) & 1, tap = i2 >> 12;
        int o = mt * 16 + (l & 15);
        int c = kt * 32 + (l >> 4) * 8 + j;
        *reinterpret_cast<unsigned short*>(w2p + i2) =
            f2bf(w2[(o * WIDTH + c) * 9 + tap]);
    } else if (idx < 16384 + 36864 + 16384) { // w3q: kt 0..1, ot 0..15
        int i3 = idx - 16384 - 36864;
        int j = i3 & 7, l = (i3 >> 3) & 63;
        int ot = (i3 >> 9) & 15, kt = i3 >> 13;
        int oc = ot * 16 + (l & 15);
        int c = kt * 32 + (l >> 4) * 8 + j;
        *reinterpret_cast<unsigned short*>(w3q + i3) = f2bf(w3[oc * WIDTH + c]);
    }
}

// ---------------------------------------------------------------------------
// k1: h1g = relu(bn1(conv1(x))) bf16 chan-last padded [58][58][64]; f32 mask.
// h1g px-rows stored pre-swizzled (u16 off ^= (pxp&7)<<3).
// ---------------------------------------------------------------------------
__global__ __launch_bounds__(256) void k1_mfma(
    const float* __restrict__ x, const __hip_bfloat16* __restrict__ w1p,
    const float* __restrict__ sc1, const float* __restrict__ sh1,
    const float* __restrict__ mw, const float* __restrict__ mb,
    __hip_bfloat16* __restrict__ h1g, float* __restrict__ mask)
{
    __shared__ __align__(16) unsigned short xs[2][64 * XSTR];
    __shared__ __align__(16) float mtab[16][68];

    const int tid = threadIdx.x;
    const int l = tid & 63, w = tid >> 6;
    const int ln = l & 15, lg = l >> 4;
    const int b = blockIdx.y;
    const int px0 = blockIdx.x * 64;
    const float* __restrict__ xb = x + (size_t)b * CIN * HW;
    const bf16x8* __restrict__ w1v = reinterpret_cast<const bf16x8*>(w1p);

    const int chA = tid >> 4;          // 0..15
    const int pxs = (tid & 15) * 4;    // 0..60
    float msum[4] = {0.f, 0.f, 0.f, 0.f};

    auto STAGE = [&](int kt, int bufi) {
        const float* xp = xb + (size_t)(kt * 32 + chA) * HW + px0 + pxs;
        float4 va = *reinterpret_cast<const float4*>(xp);
        float4 vb = *reinterpret_cast<const float4*>(xp + (size_t)16 * HW);
        float mwa = mw[kt * 32 + chA], mwb = mw[kt * 32 + 16 + chA];
        msum[0] += va.x * mwa + vb.x * mwb;
        msum[1] += va.y * mwa + vb.y * mwb;
        msum[2] += va.z * mwa + vb.z * mwb;
        msum[3] += va.w * mwa + vb.w * mwb;
        unsigned base = (unsigned)pxs * XSTR + chA;
        xs[bufi][base + 0 * XSTR] = f2bf(va.x);
        xs[bufi][base + 1 * XSTR] = f2bf(va.y);
        xs[bufi][base + 2 * XSTR] = f2bf(va.z);
        xs[bufi][base + 3 * XSTR] = f2bf(va.w);
        xs[bufi][base + 16 + 0 * XSTR] = f2bf(vb.x);
        xs[bufi][base + 16 + 1 * XSTR] = f2bf(vb.y);
        xs[bufi][base + 16 + 2 * XSTR] = f2bf(vb.z);
        xs[bufi][base + 16 + 3 * XSTR] = f2bf(vb.w);
    };

    f32x4 acc[4];
    #pragma unroll
    for (int m = 0; m < 4; ++m) acc[m] = f32x4{0.f, 0.f, 0.f, 0.f};

    STAGE(0, 0);
    __syncthreads();

    const unsigned fidx = (unsigned)(w * 16 + ln) * XSTR + lg * 8;
    #pragma unroll
    for (int kt = 0; kt < 8; ++kt) {
        const int cur = kt & 1;
        if (kt < 7) STAGE(kt + 1, cur ^ 1);
        bf16x8 bfr = *reinterpret_cast<const bf16x8*>(&xs[cur][fidx]);
        #pragma unroll
        for (int mt = 0; mt < 4; ++mt) {
            bf16x8 a = w1v[(kt * 4 + mt) * 64 + l];
            acc[mt] = __builtin_amdgcn_mfma_f32_16x16x32_bf16(a, bfr, acc[mt], 0, 0, 0);
        }
        __syncthreads();
    }

    *reinterpret_cast<float4*>(&mtab[chA][pxs]) =
        make_float4(msum[0], msum[1], msum[2], msum[3]);
    __syncthreads();
    if (tid < 64) {
        float s = 0.f;
        #pragma unroll
        for (int g = 0; g < 16; ++g) s += mtab[g][tid];
        mask[b * HW + px0 + tid] = (s + mb[0] >= 0.f) ? 1.f : 0.f;
    }

    const int p = px0 + w * 16 + ln;
    const int y = p / 56, xcn = p - y * 56;
    const int pxp = xcn + 1;                       // padded col
    const unsigned key = (unsigned)(pxp & 7) << 3; // u16-unit XOR key
    const size_t rowbase = (((size_t)b * 58 + y + 1) * 58 + pxp) * 64;
    #pragma unroll
    for (int mt = 0; mt < 4; ++mt) {
        int ob = mt * 16 + lg * 4;
        ushort4 u;
        u.x = f2bf(fmaxf(acc[mt][0] * sc1[ob + 0] + sh1[ob + 0], 0.f));
        u.y = f2bf(fmaxf(acc[mt][1] * sc1[ob + 1] + sh1[ob + 1], 0.f));
        u.z = f2bf(fmaxf(acc[mt][2] * sc1[ob + 2] + sh1[ob + 2], 0.f));
        u.w = f2bf(fmaxf(acc[mt][3] * sc1[ob + 3] + sh1[ob + 3], 0.f));
        *reinterpret_cast<ushort4*>(h1g + rowbase + (ob ^ key)) = u;
    }
}

// ---------------------------------------------------------------------------
// k2: h2 = relu(bn2(conv2(h1 * dilate(mask)))) * mask -> bf16 chan-last.
// XCD swizzle: 896 blocks, each XCD owns 112 consecutive ids = 4 images.
// ---------------------------------------------------------------------------
__global__ __launch_bounds__(256) void k2_mfma(
    const __hip_bfloat16* __restrict__ h1g,
    const __hip_bfloat16* __restrict__ w2p,
    const float* __restrict__ sc2, const float* __restrict__ sh2,
    const float* __restrict__ mask, __hip_bfloat16* __restrict__ h2)
{
    __shared__ __align__(16) char smem[30720];   // 4 rows * 7424

    const int tid = threadIdx.x;
    const int l = tid & 63, w = tid >> 6;

    const int flat = blockIdx.x + 28 * blockIdx.y;
    const int n = (flat & 7) * 112 + (flat >> 3);      // 896/8 = 112
    const int yr0 = (n % 28) * 2;
    const int b = n / 28;

    const int yrow = yr0 + (w & 1);              // output row
    const int mh = w >> 1;                       // oc half
    const int ln = l & 15, lg = l >> 4;

    {
        const char* src = (const char*)h1g + ((size_t)b * 58 + yr0) * H1ROW;
        #pragma unroll
        for (int t = 0; t < 8; ++t) {
            int c = t * 4 + w;                   // wave-uniform chunk id
            if (c < 29) {
                __builtin_amdgcn_global_load_lds(
                    (const __attribute__((address_space(1))) void*)(src + c * 1024 + l * 16),
                    (__attribute__((address_space(3))) void*)(smem + c * 1024),
                    16, 0, 0);
            }
        }
    }

    const bf16x8* __restrict__ w2v = reinterpret_cast<const bf16x8*>(w2p);

    f32x4 acc[2][4];
    #pragma unroll
    for (int i = 0; i < 2; ++i)
        #pragma unroll
        for (int j = 0; j < 4; ++j) acc[i][j] = f32x4{0.f, 0.f, 0.f, 0.f};

    __syncthreads();   // drains global_load_lds + sync

    // dilate-zero pass: 232 px = 4 rows x 58 cols
    if (tid < 232) {
        const int pr = tid / 58;
        const int pc = tid - pr * 58;
        const int gr = yr0 + pr;
        bool zero;
        if (gr == 0 || gr == 57 || pc == 0 || pc == 57) {
            zero = true;
        } else {
            const int y = gr - 1, xc = pc - 1;
            float mx = 0.f;
            #pragma unroll
            for (int dy = -1; dy <= 1; ++dy)
                #pragma unroll
                for (int dx = -1; dx <= 1; ++dx) {
                    int yy = y + dy, xx = xc + dx;
                    if (yy >= 0 && yy < HH && xx >= 0 && xx < WW)
                        mx = fmaxf(mx, mask[b * HW + yy * WW + xx]);
                }
            zero = (mx < 0.5f);
        }
        if (zero) {
            uint4* q = reinterpret_cast<uint4*>(smem + pr * H1ROW + pc * 128);
            uint4 zz = make_uint4(0u, 0u, 0u, 0u);
            #pragma unroll
            for (int k = 0; k < 8; ++k) q[k] = zz;
        }
    }
    __syncthreads();

    #pragma unroll
    for (int dy = 0; dy < 3; ++dy) {
        const int lr = (w & 1) + dy;
        #pragma unroll
        for (int dx = 0; dx < 3; ++dx) {
            const int tap = dy * 3 + dx;
            #pragma unroll
            for (int kt = 0; kt < 2; ++kt) {
                bf16x8 a0 = w2v[((tap * 2 + kt) * 4 + mh * 2 + 0) * 64 + l];
                bf16x8 a1 = w2v[((tap * 2 + kt) * 4 + mh * 2 + 1) * 64 + l];
                bf16x8 bf[4];
                #pragma unroll
                for (int nt = 0; nt < 4; ++nt) {
                    int colp = nt * 16 + ln + dx;
                    unsigned off = (unsigned)lr * H1ROW + (unsigned)colp * 128
                                 + (((unsigned)(kt * 64 + lg * 16))
                                    ^ (((unsigned)colp & 7u) << 4));
                    bf[nt] = *reinterpret_cast<const bf16x8*>(smem + off);
                }
                #pragma unroll
                for (int nt = 0; nt < 4; ++nt) {
                    acc[0][nt] = __builtin_amdgcn_mfma_f32_16x16x32_bf16(
                        a0, bf[nt], acc[0][nt], 0, 0, 0);
                    acc[1][nt] = __builtin_amdgcn_mfma_f32_16x16x32_bf16(
                        a1, bf[nt], acc[1][nt], 0, 0, 0);
                }
            }
        }
    }

    #pragma unroll
    for (int nt = 0; nt < 4; ++nt) {
        int xc = nt * 16 + ln;
        if (xc < WW) {
            int p = yrow * WW + xc;
            float mkv = mask[b * HW + p];
            #pragma unroll
            for (int mi = 0; mi < 2; ++mi) {
                int ob = (mh * 2 + mi) * 16 + lg * 4;
                ushort4 u;
                u.x = f2bf(fmaxf(acc[mi][nt][0] * sc2[ob + 0] + sh2[ob + 0], 0.f) * mkv);
                u.y = f2bf(fmaxf(acc[mi][nt][1] * sc2[ob + 1] + sh2[ob + 1], 0.f) * mkv);
                u.z = f2bf(fmaxf(acc[mi][nt][2] * sc2[ob + 2] + sh2[ob + 2], 0.f) * mkv);
                u.w = f2bf(fmaxf(acc[mi][nt][3] * sc2[ob + 3] + sh2[ob + 3], 0.f) * mkv);
                *reinterpret_cast<ushort4*>(h2 + ((size_t)b * HW + p) * 64 + ob) = u;
            }
        }
    }
}

// ---------------------------------------------------------------------------
// k3: out = relu(x + bn3(conv3(h2)) * mask). LDS f32 h3s + row-contiguous
// phase 2 + XCD swizzle (each XCD owns 448 consecutive ids = disjoint slabs).
// ---------------------------------------------------------------------------
__global__ __launch_bounds__(256) void k3_mfma(
    const __hip_bfloat16* __restrict__ h2, const __hip_bfloat16* __restrict__ w3q,
    const float* __restrict__ sc3, const float* __restrict__ sh3,
    const float* __restrict__ x, const float* __restrict__ mask,
    float* __restrict__ out)
{
    __shared__ __align__(16) float h3s[128][68];   // 34816 B

    const int tid = threadIdx.x;
    const int l = tid & 63, w = tid >> 6;
    const int ln = l & 15, lg = l >> 4;

    const int flat = blockIdx.x + 56 * (blockIdx.y + 32 * blockIdx.z);
    const int n = (flat & 7) * 448 + (flat >> 3);      // 3584/8 = 448
    const int yr = n % 56;
    const int b = (n / 56) & 31;
    const int z = n / (56 * 32);

    const bf16x8* __restrict__ h2v = reinterpret_cast<const bf16x8*>(h2)
                                   + ((size_t)b * HW + yr * WW) * 8;
    const bf16x8* __restrict__ w3v = reinterpret_cast<const bf16x8*>(w3q);

    // ---- phase 1: MFMA ----
    bf16x8 af[2][4];   // [kt][pt]
    #pragma unroll
    for (int kt = 0; kt < 2; ++kt)
        #pragma unroll
        for (int pt = 0; pt < 4; ++pt)
            af[kt][pt] = h2v[(pt * 16 + ln) * 8 + kt * 4 + lg];  // px>=56 overread OK
    bf16x8 bw[2][2];   // [kt][ot]
    #pragma unroll
    for (int kt = 0; kt < 2; ++kt)
        #pragma unroll
        for (int ot = 0; ot < 2; ++ot)
            bw[kt][ot] = w3v[(kt * 16 + w * 4 + z * 2 + ot) * 64 + l];

    f32x4 acc[4][2];   // [pt][ot]
    #pragma unroll
    for (int p = 0; p < 4; ++p)
        #pragma unroll
        for (int o = 0; o < 2; ++o) acc[p][o] = f32x4{0.f, 0.f, 0.f, 0.f};

    #pragma unroll
    for (int kt = 0; kt < 2; ++kt)
        #pragma unroll
        for (int ot = 0; ot < 2; ++ot)
            #pragma unroll
            for (int pt = 0; pt < 4; ++pt)
                acc[pt][ot] = __builtin_amdgcn_mfma_f32_16x16x32_bf16(
                    af[kt][pt], bw[kt][ot], acc[pt][ot], 0, 0, 0);

    // ---- dump raw acc to LDS (px 56..63 garbage, never read) ----
    #pragma unroll
    for (int ot = 0; ot < 2; ++ot) {
        const int r = w * 32 + ot * 16 + ln;
        #pragma unroll
        for (int pt = 0; pt < 4; ++pt)
            *reinterpret_cast<f32x4*>(&h3s[r][pt * 16 + lg * 4]) = acc[pt][ot];
    }
    __syncthreads();

    // ---- phase 2: row-contiguous residual + store ----
    const int tc = tid & 15, tr0 = tid >> 4;
    if (tc < 14) {
        const int px4 = tc * 4;
        const float4 mk = *reinterpret_cast<const float4*>(
            &mask[(size_t)b * HW + yr * WW + px4]);
        #pragma unroll
        for (int pass = 0; pass < 8; ++pass) {
            const int r = pass * 16 + tr0;
            const int oc = ((r >> 5) << 6) + z * 32 + (r & 31);
            const float4 v = *reinterpret_cast<const float4*>(&h3s[r][px4]);
            const float sc = sc3[oc], sh = sh3[oc];
            const size_t idx = ((size_t)b * COUT + oc) * HW + yr * WW + px4;
            const float4 xv = *reinterpret_cast<const float4*>(&x[idx]);
            float4 o4;
            o4.x = fmaxf(xv.x + (v.x * sc + sh) * mk.x, 0.f);
            o4.y = fmaxf(xv.y + (v.y * sc + sh) * mk.y, 0.f);
            o4.z = fmaxf(xv.z + (v.z * sc + sh) * mk.z, 0.f);
            o4.w = fmaxf(xv.w + (v.w * sc + sh) * mk.w, 0.f);
            *reinterpret_cast<float4*>(&out[idx]) = o4;
        }
    }
}

// ---------------------------------------------------------------------------
extern "C" void kernel_launch(void* const* d_in, const int* in_sizes, int n_in,
                              void* d_out, int out_size, void* d_ws, size_t ws_size,
                              hipStream_t stream)
{
    const float* x  = (const float*)d_in[0];
    const float* w1 = (const float*)d_in[1];
    const float* w2 = (const float*)d_in[2];
    const float* w3 = (const float*)d_in[3];
    const float* g1 = (const float*)d_in[4];
    const float* b1 = (const float*)d_in[5];
    const float* m1 = (const float*)d_in[6];
    const float* v1 = (const float*)d_in[7];
    const float* g2 = (const float*)d_in[8];
    const float* b2 = (const float*)d_in[9];
    const float* m2 = (const float*)d_in[10];
    const float* v2 = (const float*)d_in[11];
    const float* g3 = (const float*)d_in[12];
    const float* b3 = (const float*)d_in[13];
    const float* m3 = (const float*)d_in[14];
    const float* v3 = (const float*)d_in[15];
    const float* mw = (const float*)d_in[16];
    const float* mb = (const float*)d_in[17];
    float* outp = (float*)d_out;

    // ws layout
    char* p = (char*)d_ws;
    __hip_bfloat16* h1g = (__hip_bfloat16*)p;  p += (size_t)BATCH * 3364 * 64 * 2; // 13.8 MB
    __hip_bfloat16* h2  = (__hip_bfloat16*)p;  p += (size_t)BATCH * HW * 64 * 2;   // 12.8 MB
    float* mask = (float*)p;                   p += (size_t)BATCH * HW * 4;        // 0.4 MB
    __hip_bfloat16* w1p = (__hip_bfloat16*)p;  p += 16384 * 2;
    __hip_bfloat16* w2p = (__hip_bfloat16*)p;  p += 36864 * 2;
    __hip_bfloat16* w3q = (__hip_bfloat16*)p;  p += 16384 * 2;
    float* tabs = (float*)p;
    float* sc1 = tabs;       float* sh1 = tabs + 64;
    float* sc2 = tabs + 128; float* sh2 = tabs + 192;
    float* sc3 = tabs + 256; float* sh3 = tabs + 512;

    kw_pack<<<dim3(273), dim3(256), 0, stream>>>(w1, w2, w3, w1p, w2p, w3q,
                                                 g1, b1, m1, v1, g2, b2, m2, v2,
                                                 g3, b3, m3, v3, tabs);

    k1_mfma<<<dim3(49, BATCH), dim3(256), 0, stream>>>(x, w1p, sc1, sh1, mw, mb,
                                                       h1g, mask);

    k2_mfma<<<dim3(28, BATCH), dim3(256), 0, stream>>>(h1g, w2p, sc2, sh2,
                                                       mask, h2);

    k3_mfma<<<dim3(HH, BATCH, 2), dim3(256), 0, stream>>>(h2, w3q, sc3, sh3,
                                                          x, mask, outp);
}